// Round 7
// baseline (595.042 us; speedup 1.0000x reference)
//
#include <hip/hip_runtime.h>
#include <hip/hip_bf16.h>

#define MN 16384
#define SPLITS 4
#define KSLICE (MN / SPLITS)     // 4096
#define BK 128
#define NSTEPS (KSLICE / BK)     // 32

typedef float f32x4 __attribute__((ext_vector_type(4)));
typedef int   i32x4 __attribute__((ext_vector_type(4)));

#define A8S 32768.0f             // adj * 2^15 in [0,2)
#define SB1 64.0f                // support1 * 64
#define SB2 4096.0f              // support2 * 4096
#define SC1 (1.0f / (32768.0f * 64.0f))     // 2^-21
#define SC2 (1.0f / (32768.0f * 4096.0f))   // 2^-27

__device__ __forceinline__ void async16(void* lds, const void* g) {
  __builtin_amdgcn_global_load_lds(
      (const __attribute__((address_space(1))) unsigned int*)g,
      (__attribute__((address_space(3))) unsigned int*)lds, 16, 0, 0);
}

// fp8-fragment order for a [K x 128] operand: byte[(U*128 + col)*8 + j]
// holds fp8(val[k = U*8 + j][col]).  (unit U = k>>3, j = k&7)

// ---------------------------------------------------------------------------
// K1: support1 = x @ W2 -> fp8 e4m3 (x SB1) in fragment order.
// ---------------------------------------------------------------------------
__global__ __launch_bounds__(256)
void k1_xw2(const float* __restrict__ x, const float* __restrict__ W2,
            unsigned char* __restrict__ B1) {
  __shared__ __align__(16) float xs[64 * 128];
  const int t = threadIdx.x;
  const long rowbase = (long)blockIdx.x * 64;
  const f32x4* xg = (const f32x4*)(x + rowbase * 128);
  f32x4* xl = (f32x4*)xs;
#pragma unroll
  for (int i = 0; i < 8; ++i) xl[t + 256 * i] = xg[t + 256 * i];
  __syncthreads();
  const int r0 = (t >> 5) * 8;   // 8 rows per thread (8-aligned)
  const int c0 = (t & 31) * 4;   // 4 cols per thread
  float acc[8][4] = {};
  for (int k = 0; k < 128; k += 4) {
    f32x4 w[4];
#pragma unroll
    for (int kk = 0; kk < 4; ++kk) w[kk] = *(const f32x4*)(W2 + (k + kk) * 128 + c0);
#pragma unroll
    for (int i = 0; i < 8; ++i) {
      f32x4 xv = *(const f32x4*)(xs + (r0 + i) * 128 + k);
#pragma unroll
      for (int kk = 0; kk < 4; ++kk)
#pragma unroll
        for (int j = 0; j < 4; ++j) acc[i][j] += xv[kk] * w[kk][j];
    }
  }
  const long U = (rowbase + r0) >> 3;
  i32x4 wv0, wv1;
#pragma unroll
  for (int j = 0; j < 4; ++j) {
    int lo = __builtin_amdgcn_cvt_pk_fp8_f32(acc[0][j] * SB1, acc[1][j] * SB1, 0, false);
    lo     = __builtin_amdgcn_cvt_pk_fp8_f32(acc[2][j] * SB1, acc[3][j] * SB1, lo, true);
    int hi = __builtin_amdgcn_cvt_pk_fp8_f32(acc[4][j] * SB1, acc[5][j] * SB1, 0, false);
    hi     = __builtin_amdgcn_cvt_pk_fp8_f32(acc[6][j] * SB1, acc[7][j] * SB1, hi, true);
    if (j < 2) { wv0[2 * j] = lo; wv0[2 * j + 1] = hi; }
    else       { wv1[2 * (j - 2)] = lo; wv1[2 * (j - 2) + 1] = hi; }
  }
  *(i32x4*)(B1 + (U * 128 + c0) * 8)      = wv0;
  *(i32x4*)(B1 + (U * 128 + c0) * 8 + 16) = wv1;
}

// ---------------------------------------------------------------------------
// Big kernel v7: P[s] = adj[:, k-slice s] @ B, fp8 e4m3 MFMA.
// 512 threads / 8 waves; 128-row tile; BK=128 outer steps (32 steps).
// K-relabel: lane(g,cl) owns k = T*128 + 32g + [0,32): 128B contiguous f32
// per lane per step (8 back-to-back dwordx4) -> 512B per DRAM-row visit.
// MFMA j (j=0..3) uses lane chunk j (pk dwords 2j,2j+1); matching B unit is
// (16T + 4g + j), i.e. LDS piece g at offset j*1024 — stage stays LINEAR.
// AMODE 0: A f32 -> cvt fp8 once; bytes feed MFMA + A8 side-copy (32B/lane).
// AMODE 1: A from fp8 copy (2 dwordx4/lane/step), prefetched 1 step ahead.
// AMODE 2: AMODE 0 without the side-copy (ws fallback).
// Sync: 2-deep 16KB LDS double-buffer; stage(T+1) issued FIRST (pinned by
// sched_barrier); AMODE 0/2: compiler's A(T)-wait (younger than stage)
// retires stage(T+1) before the raw barrier — no explicit vmcnt needed.
// AMODE 1 (A prefetched, nothing else waits): explicit vmcnt(2) keeps the
// 2 A(T+1) loads in flight while retiring stage(T+1).
// ---------------------------------------------------------------------------
template <int AMODE>
__global__ __launch_bounds__(512, 4)
void big_mm(const float* __restrict__ A, const unsigned char* __restrict__ A8r,
            unsigned char* __restrict__ A8w, const unsigned char* __restrict__ B8,
            float sc, float* __restrict__ P) {
  __shared__ __align__(16) unsigned char Bs[2][16384];
  const int tid  = threadIdx.x;
  const int wid  = tid >> 6;     // 0..7
  const int lane = tid & 63;
  const int g    = lane >> 4;    // k-group
  const int cl   = lane & 15;    // A-row / B-col / C-col within tile
  const int tile_m = blockIdx.x & 127;
  const int s      = blockIdx.x >> 7;
  const long k0 = (long)s * KSLICE;

  const char* bsrc = (const char*)B8 + k0 * 128 + (long)tid * 16;
  const float* aptr = nullptr;
  if constexpr (AMODE != 1)
    aptr = A + (long)(tile_m * 128 + wid * 16 + cl) * MN + k0 + 32 * g;
  const long c8base = (long)blockIdx.x * (NSTEPS * 16384L) + (long)tid * 32;

  f32x4 acc[8] = {};

  // prologue: stage step 0 into buf 0; prefetch A(0) for AMODE 1; full drain
  {
    unsigned char* d = &Bs[0][0] + wid * 1024;
    async16(d, bsrc);
    async16(d + 8192, bsrc + 8192);
  }
  i32x4 av0, av1;
  if constexpr (AMODE == 1) {
    av0 = *(const i32x4*)(A8r + c8base);
    av1 = *(const i32x4*)(A8r + c8base + 16);
  }
  __syncthreads();

  for (int T = 0; T < NSTEPS; ++T) {
    // (1) stage B(T+1) FIRST — must be older than this step's A traffic
    if (T + 1 < NSTEPS) {
      unsigned char* d = &Bs[(T + 1) & 1][0] + wid * 1024;
      const char* src = bsrc + (long)(T + 1) * 16384;
      async16(d, src);
      async16(d + 8192, src + 8192);
    }
    __builtin_amdgcn_sched_barrier(0);   // pin stage < A-load issue order

    int pk[8];
    i32x4 nav0, nav1;
    if constexpr (AMODE == 1) {
      if (T + 1 < NSTEPS) {
        const unsigned char* ap = A8r + c8base + (long)(T + 1) * 16384;
        nav0 = *(const i32x4*)ap;
        nav1 = *(const i32x4*)(ap + 16);
      }
      pk[0] = av0[0]; pk[1] = av0[1]; pk[2] = av0[2]; pk[3] = av0[3];
      pk[4] = av1[0]; pk[5] = av1[1]; pk[6] = av1[2]; pk[7] = av1[3];
    } else {
      const float* ap = aptr + (long)T * BK;
      f32x4 av[8];
#pragma unroll
      for (int i = 0; i < 8; ++i) av[i] = *(const f32x4*)(ap + 4 * i);
#pragma unroll
      for (int d = 0; d < 8; ++d) {
        int w = __builtin_amdgcn_cvt_pk_fp8_f32(av[d][0] * A8S, av[d][1] * A8S, 0, false);
        pk[d] = __builtin_amdgcn_cvt_pk_fp8_f32(av[d][2] * A8S, av[d][3] * A8S, w, true);
      }
      if constexpr (AMODE == 0) {
        i32x4 s1 = {pk[0], pk[1], pk[2], pk[3]};
        i32x4 s2 = {pk[4], pk[5], pk[6], pk[7]};
        unsigned char* wp = A8w + c8base + (long)T * 16384;
        __builtin_nontemporal_store(s1, (i32x4*)wp);
        __builtin_nontemporal_store(s2, (i32x4*)(wp + 16));
      }
    }

    // MFMA: 4 k-chunks x 8 col-tiles; chunk j <-> LDS piece g, offset j*1024
    const char* bb = (const char*)&Bs[T & 1][0] + g * 4096 + cl * 8;
#pragma unroll
    for (int j = 0; j < 4; ++j) {
      const long a = ((long)(unsigned)pk[2 * j + 1] << 32) | (unsigned)pk[2 * j];
#pragma unroll
      for (int c = 0; c < 8; ++c) {
        long b = *(const long*)(bb + j * 1024 + c * 128);
        acc[c] = __builtin_amdgcn_mfma_f32_16x16x32_fp8_fp8(a, b, acc[c], 0, 0, 0);
      }
    }

    if constexpr (AMODE == 1) {
      if (T + 1 < NSTEPS) asm volatile("s_waitcnt vmcnt(2)" ::: "memory");
      av0 = nav0; av1 = nav1;
    }
    __builtin_amdgcn_s_barrier();   // raw barrier: no vmcnt(0) drain
  }

  // C/D layout (HW-verified, dtype-independent): col=lane&15, row=4*(lane>>4)+q
  float* pb = P + ((long)s * MN + tile_m * 128 + wid * 16) * 128;
#pragma unroll
  for (int c = 0; c < 8; ++c)
#pragma unroll
    for (int q = 0; q < 4; ++q)
      __builtin_nontemporal_store(acc[c][q] * sc,
                                  &pb[(g * 4 + q) * 128 + 16 * c + cl]);
}

// ---------------------------------------------------------------------------
// K3: LH = sum_s P[s] + b2 (tile in LDS); then
//     B2 = fp8frag(LH @ W4 * SB2);  R = LH @ res_w^T + res_b + b4
// ---------------------------------------------------------------------------
__global__ __launch_bounds__(256)
void k3_mid(const float* __restrict__ P, const float* __restrict__ b2,
            const float* __restrict__ W4, const float* __restrict__ res_w,
            const float* __restrict__ b4, const float* __restrict__ res_b,
            unsigned char* __restrict__ B2, float* __restrict__ Rr) {
  __shared__ __align__(16) float hs[64 * 128];
  const int t = threadIdx.x;
  const long rowbase = (long)blockIdx.x * 64;
  const long base = rowbase * 32;            // f32x4 units (128/4 per row)
  const f32x4* P0 = (const f32x4*)P + base;
  const f32x4* P1 = (const f32x4*)P + (long)MN * 32 + base;
  const f32x4* P2 = (const f32x4*)P + 2L * MN * 32 + base;
  const f32x4* P3 = (const f32x4*)P + 3L * MN * 32 + base;
  const f32x4* b2v = (const f32x4*)b2;
  f32x4* hl = (f32x4*)hs;
#pragma unroll
  for (int i = 0; i < 8; ++i) {
    int idx = t + 256 * i;
    f32x4 v = __builtin_nontemporal_load(P0 + idx);
    v += __builtin_nontemporal_load(P1 + idx);
    v += __builtin_nontemporal_load(P2 + idx);
    v += __builtin_nontemporal_load(P3 + idx);
    hl[idx] = v + b2v[idx & 31];
  }
  __syncthreads();
  const int r0 = (t >> 5) * 8;
  const int c0 = (t & 31) * 4;
  float acc2[8][4] = {};
  float accR[8][4] = {};
  for (int k = 0; k < 128; k += 4) {
    f32x4 w4v[4], rwv[4];
#pragma unroll
    for (int kk = 0; kk < 4; ++kk) w4v[kk] = *(const f32x4*)(W4 + (k + kk) * 128 + c0);
#pragma unroll
    for (int j = 0; j < 4; ++j) rwv[j] = *(const f32x4*)(res_w + (c0 + j) * 128 + k);
#pragma unroll
    for (int i = 0; i < 8; ++i) {
      f32x4 xv = *(const f32x4*)(hs + (r0 + i) * 128 + k);
#pragma unroll
      for (int kk = 0; kk < 4; ++kk)
#pragma unroll
        for (int j = 0; j < 4; ++j) {
          acc2[i][j] += xv[kk] * w4v[kk][j];
          accR[i][j] += xv[kk] * rwv[j][kk];
        }
    }
  }
  const long U = (rowbase + r0) >> 3;
  i32x4 wv0, wv1;
#pragma unroll
  for (int j = 0; j < 4; ++j) {
    int lo = __builtin_amdgcn_cvt_pk_fp8_f32(acc2[0][j] * SB2, acc2[1][j] * SB2, 0, false);
    lo     = __builtin_amdgcn_cvt_pk_fp8_f32(acc2[2][j] * SB2, acc2[3][j] * SB2, lo, true);
    int hi = __builtin_amdgcn_cvt_pk_fp8_f32(acc2[4][j] * SB2, acc2[5][j] * SB2, 0, false);
    hi     = __builtin_amdgcn_cvt_pk_fp8_f32(acc2[6][j] * SB2, acc2[7][j] * SB2, hi, true);
    if (j < 2) { wv0[2 * j] = lo; wv0[2 * j + 1] = hi; }
    else       { wv1[2 * (j - 2)] = lo; wv1[2 * (j - 2) + 1] = hi; }
  }
  *(i32x4*)(B2 + (U * 128 + c0) * 8)      = wv0;
  *(i32x4*)(B2 + (U * 128 + c0) * 8 + 16) = wv1;

  const f32x4 b4v = *(const f32x4*)(b4 + c0);
  const f32x4 rbv = *(const f32x4*)(res_b + c0);
#pragma unroll
  for (int i = 0; i < 8; ++i) {
    f32x4 rv;
#pragma unroll
    for (int j = 0; j < 4; ++j) rv[j] = accR[i][j];
    rv += b4v + rbv;
    *(f32x4*)(Rr + (rowbase + r0 + i) * 128 + c0) = rv;
  }
}

// ---------------------------------------------------------------------------
// K5: out = sum_s P[s] + R
// ---------------------------------------------------------------------------
__global__ __launch_bounds__(256)
void k5_out(const float* __restrict__ P, const float* __restrict__ Rr,
            float* __restrict__ out) {
  const long i = (long)blockIdx.x * 256 + threadIdx.x;   // f32x4 index
  const f32x4* P0 = (const f32x4*)P;
  const f32x4* P1 = P0 + (long)MN * 32;
  const f32x4* P2 = P0 + 2L * MN * 32;
  const f32x4* P3 = P0 + 3L * MN * 32;
  f32x4 v = __builtin_nontemporal_load(P0 + i);
  v += __builtin_nontemporal_load(P1 + i);
  v += __builtin_nontemporal_load(P2 + i);
  v += __builtin_nontemporal_load(P3 + i);
  v += *((const f32x4*)Rr + i);
  __builtin_nontemporal_store(v, (f32x4*)out + i);
}

extern "C" void kernel_launch(void* const* d_in, const int* in_sizes, int n_in,
                              void* d_out, int out_size, void* d_ws, size_t ws_size,
                              hipStream_t stream) {
  const float* x     = (const float*)d_in[0];
  const float* adj   = (const float*)d_in[1];
  const float* W2    = (const float*)d_in[2];
  const float* b2    = (const float*)d_in[3];
  const float* W4    = (const float*)d_in[4];
  const float* b4    = (const float*)d_in[5];
  const float* res_w = (const float*)d_in[6];
  const float* res_b = (const float*)d_in[7];
  float* out = (float*)d_out;

  char* ws = (char*)d_ws;
  unsigned char* B1 = (unsigned char*)ws;                  // 2 MB fp8-frag support1
  unsigned char* B2 = (unsigned char*)(ws + (4L << 20));   // 2 MB fp8-frag support2
  float* Rr = (float*)(ws + (8L << 20));                   // 8 MB residual + biases
  float* P  = (float*)(ws + (16L << 20));                  // 32 MB split-K partials
  unsigned char* A8 = (unsigned char*)(ws + (48L << 20));  // 256 MB fp8 adj

  const size_t need = (48L << 20) + (size_t)MN * MN;  // 318.8 MB
  const bool fp8_copy = ws_size >= need;

  k1_xw2<<<dim3(256), dim3(256), 0, stream>>>(x, W2, B1);
  if (fp8_copy) {
    big_mm<0><<<dim3(128 * SPLITS), dim3(512), 0, stream>>>(adj, nullptr, A8, B1, SC1, P);
    k3_mid<<<dim3(256), dim3(256), 0, stream>>>(P, b2, W4, res_w, b4, res_b, B2, Rr);
    big_mm<1><<<dim3(128 * SPLITS), dim3(512), 0, stream>>>(nullptr, A8, nullptr, B2, SC2, P);
  } else {
    big_mm<2><<<dim3(128 * SPLITS), dim3(512), 0, stream>>>(adj, nullptr, nullptr, B1, SC1, P);
    k3_mid<<<dim3(256), dim3(256), 0, stream>>>(P, b2, W4, res_w, b4, res_b, B2, Rr);
    big_mm<2><<<dim3(128 * SPLITS), dim3(512), 0, stream>>>(adj, nullptr, nullptr, B2, SC2, P);
  }
  k5_out<<<dim3(2048), dim3(256), 0, stream>>>(P, Rr, out);
}

// Round 8
// 429.865 us; speedup vs baseline: 1.3843x; 1.3843x over previous
//
#include <hip/hip_runtime.h>
#include <hip/hip_bf16.h>

#define MN 16384
#define SPLITS 4
#define KSLICE (MN / SPLITS)     // 4096
#define BK 64
#define NSTEPS (KSLICE / BK)     // 64
#define NSUPER (NSTEPS / 2)      // 32

typedef float f32x4 __attribute__((ext_vector_type(4)));
typedef int   i32x4 __attribute__((ext_vector_type(4)));

#define A8S 32768.0f             // adj * 2^15 in [0,2)
#define SB1 64.0f                // support1 * 64
#define SB2 4096.0f              // support2 * 4096
#define SC1 (1.0f / (32768.0f * 64.0f))     // 2^-21
#define SC2 (1.0f / (32768.0f * 4096.0f))   // 2^-27

__device__ __forceinline__ void async16(void* lds, const void* g) {
  __builtin_amdgcn_global_load_lds(
      (const __attribute__((address_space(1))) unsigned int*)g,
      (__attribute__((address_space(3))) unsigned int*)lds, 16, 0, 0);
}

// fp8-fragment order for a [K x 128] operand: byte[(U*128 + col)*8 + j]
// holds fp8(val[k = U*8 + j][col]).  (unit U = k>>3, j = k&7)

// ---------------------------------------------------------------------------
// K1: support1 = x @ W2 -> fp8 e4m3 (x SB1) in fragment order.
// ---------------------------------------------------------------------------
__global__ __launch_bounds__(256)
void k1_xw2(const float* __restrict__ x, const float* __restrict__ W2,
            unsigned char* __restrict__ B1) {
  __shared__ __align__(16) float xs[64 * 128];
  const int t = threadIdx.x;
  const long rowbase = (long)blockIdx.x * 64;
  const f32x4* xg = (const f32x4*)(x + rowbase * 128);
  f32x4* xl = (f32x4*)xs;
#pragma unroll
  for (int i = 0; i < 8; ++i) xl[t + 256 * i] = xg[t + 256 * i];
  __syncthreads();
  const int r0 = (t >> 5) * 8;   // 8 rows per thread (8-aligned)
  const int c0 = (t & 31) * 4;   // 4 cols per thread
  float acc[8][4] = {};
  for (int k = 0; k < 128; k += 4) {
    f32x4 w[4];
#pragma unroll
    for (int kk = 0; kk < 4; ++kk) w[kk] = *(const f32x4*)(W2 + (k + kk) * 128 + c0);
#pragma unroll
    for (int i = 0; i < 8; ++i) {
      f32x4 xv = *(const f32x4*)(xs + (r0 + i) * 128 + k);
#pragma unroll
      for (int kk = 0; kk < 4; ++kk)
#pragma unroll
        for (int j = 0; j < 4; ++j) acc[i][j] += xv[kk] * w[kk][j];
    }
  }
  const long U = (rowbase + r0) >> 3;
  i32x4 wv0, wv1;
#pragma unroll
  for (int j = 0; j < 4; ++j) {
    int lo = __builtin_amdgcn_cvt_pk_fp8_f32(acc[0][j] * SB1, acc[1][j] * SB1, 0, false);
    lo     = __builtin_amdgcn_cvt_pk_fp8_f32(acc[2][j] * SB1, acc[3][j] * SB1, lo, true);
    int hi = __builtin_amdgcn_cvt_pk_fp8_f32(acc[4][j] * SB1, acc[5][j] * SB1, 0, false);
    hi     = __builtin_amdgcn_cvt_pk_fp8_f32(acc[6][j] * SB1, acc[7][j] * SB1, hi, true);
    if (j < 2) { wv0[2 * j] = lo; wv0[2 * j + 1] = hi; }
    else       { wv1[2 * (j - 2)] = lo; wv1[2 * (j - 2) + 1] = hi; }
  }
  *(i32x4*)(B1 + (U * 128 + c0) * 8)      = wv0;
  *(i32x4*)(B1 + (U * 128 + c0) * 8 + 16) = wv1;
}

// ---------------------------------------------------------------------------
// Big kernel v8 = R6 structure + super-steps of 2 (32 barriers, not 64).
// 256 threads / 4 waves; 64-row tile; BK=64; fp8 e4m3 MFMA.
// LDS: 2 banks x 16 KB, each bank = 2 K-steps of B (8 KB/step).
// Per super-step m: (1) stage BOTH steps of bank (m+1)&1 FIRST (pinned by
// sched_barrier); (2) compute steps 2m, 2m+1 from bank m&1, A reg-prefetched
// 1 step ahead (R6 scheme); (3) counted vmcnt retiring exactly this
// super-step's stages (in-order retirement; A prefetch + stores stay in
// flight); (4) one raw s_barrier.
// AMODE 0: A f32 -> cvt fp8 once; bytes feed MFMA + A8 side-copy.
// AMODE 1: A from fp8 copy (1 dwordx4/lane/step, prefetched 1 step).
// AMODE 2: AMODE 0 without the side-copy (ws fallback).
// ---------------------------------------------------------------------------
template <int AMODE>
__global__ __launch_bounds__(256, 4)
void big_mm(const float* __restrict__ A, const unsigned char* __restrict__ A8r,
            unsigned char* __restrict__ A8w, const unsigned char* __restrict__ B8,
            float sc, float* __restrict__ P) {
  __shared__ __align__(16) unsigned char Bs[2][16384];
  const int tid  = threadIdx.x;
  const int wid  = tid >> 6;
  const int lane = tid & 63;
  const int g    = lane >> 4;    // k-group
  const int cl   = lane & 15;    // A-row / B-col / C-col within tile
  const int tile_m = blockIdx.x & 255;
  const int s      = blockIdx.x >> 8;
  const long k0 = (long)s * KSLICE;

  const char* bsrc = (const char*)B8 + k0 * 128 + (long)tid * 16;
  const float* aptr = nullptr;
  if constexpr (AMODE != 1)
    aptr = A + (long)(tile_m * 64 + wid * 16 + cl) * MN + k0 + 16 * g;
  const long c8base = (long)blockIdx.x * (64L * 4096) + (long)tid * 16;

  f32x4 acc[8] = {};

  // prologue: stage steps 0,1 into bank 0; prefetch A(0); one-time full drain
  {
    unsigned char* d = &Bs[0][0] + wid * 1024;
    async16(d, bsrc);                 async16(d + 4096, bsrc + 4096);
    async16(d + 8192, bsrc + 8192);   async16(d + 12288, bsrc + 12288);
  }
  f32x4 a0n, a1n, a2n, a3n;
  i32x4 q8n;
  if constexpr (AMODE == 1) {
    q8n = *(const i32x4*)(A8r + c8base);
  } else {
    a0n = *(const f32x4*)aptr;       a1n = *(const f32x4*)(aptr + 4);
    a2n = *(const f32x4*)(aptr + 8); a3n = *(const f32x4*)(aptr + 12);
  }
  __syncthreads();

  for (int m = 0; m < NSUPER; ++m) {
    // (1) stage next super-step's 2 B-steps into bank (m+1)&1 — issued FIRST
    if (m + 1 < NSUPER) {
      unsigned char* d = &Bs[(m + 1) & 1][0] + wid * 1024;
      const char* src = bsrc + (long)(2 * m + 2) * 8192;
      async16(d, src);                 async16(d + 4096, src + 4096);
      async16(d + 8192, src + 8192);   async16(d + 12288, src + 12288);
    }
    __builtin_amdgcn_sched_barrier(0);   // pin stages oldest in VMEM order

    // (2) two K-steps from bank m&1
#pragma unroll
    for (int h = 0; h < 2; ++h) {
      const int t = 2 * m + h;
      int pk0, pk1, pk2, pk3;
      if constexpr (AMODE == 1) {
        i32x4 q8 = q8n;
        if (t + 1 < NSTEPS)
          q8n = *(const i32x4*)(A8r + c8base + (long)(t + 1) * 4096);
        pk0 = q8[0]; pk1 = q8[1]; pk2 = q8[2]; pk3 = q8[3];
      } else {
        f32x4 a0 = a0n, a1 = a1n, a2 = a2n, a3 = a3n;
        if (t + 1 < NSTEPS) {
          const float* ap = aptr + (long)(t + 1) * BK;
          a0n = *(const f32x4*)ap;       a1n = *(const f32x4*)(ap + 4);
          a2n = *(const f32x4*)(ap + 8); a3n = *(const f32x4*)(ap + 12);
        }
        pk0 = __builtin_amdgcn_cvt_pk_fp8_f32(a0[0] * A8S, a0[1] * A8S, 0, false);
        pk0 = __builtin_amdgcn_cvt_pk_fp8_f32(a0[2] * A8S, a0[3] * A8S, pk0, true);
        pk1 = __builtin_amdgcn_cvt_pk_fp8_f32(a1[0] * A8S, a1[1] * A8S, 0, false);
        pk1 = __builtin_amdgcn_cvt_pk_fp8_f32(a1[2] * A8S, a1[3] * A8S, pk1, true);
        pk2 = __builtin_amdgcn_cvt_pk_fp8_f32(a2[0] * A8S, a2[1] * A8S, 0, false);
        pk2 = __builtin_amdgcn_cvt_pk_fp8_f32(a2[2] * A8S, a2[3] * A8S, pk2, true);
        pk3 = __builtin_amdgcn_cvt_pk_fp8_f32(a3[0] * A8S, a3[1] * A8S, 0, false);
        pk3 = __builtin_amdgcn_cvt_pk_fp8_f32(a3[2] * A8S, a3[3] * A8S, pk3, true);
        if constexpr (AMODE == 0) {
          i32x4 st = {pk0, pk1, pk2, pk3};
          __builtin_nontemporal_store(st, (i32x4*)(A8w + c8base + (long)t * 4096));
        }
      }
      const long alo = ((long)(unsigned)pk1 << 32) | (unsigned)pk0;
      const long ahi = ((long)(unsigned)pk3 << 32) | (unsigned)pk2;

      const char* bb = (const char*)&Bs[m & 1][0] + h * 8192 + g * 2048 + cl * 8;
#pragma unroll
      for (int c = 0; c < 8; ++c) {
        long b0 = *(const long*)(bb + c * 128);          // unit 2g
        long b1 = *(const long*)(bb + 1024 + c * 128);   // unit 2g+1
        acc[c] = __builtin_amdgcn_mfma_f32_16x16x32_fp8_fp8(alo, b0, acc[c], 0, 0, 0);
        acc[c] = __builtin_amdgcn_mfma_f32_16x16x32_fp8_fp8(ahi, b1, acc[c], 0, 0, 0);
      }
    }

    // (3) retire this super-step's stages exactly; keep A prefetch + stores
    // in flight. Younger-than-last-stage counts: AMODE0 = 8 A-loads + 2
    // stores = 10; AMODE2 = 8; AMODE1 = 2.
    if (m + 1 < NSUPER) {
      if constexpr (AMODE == 0)      asm volatile("s_waitcnt vmcnt(10)" ::: "memory");
      else if constexpr (AMODE == 2) asm volatile("s_waitcnt vmcnt(8)" ::: "memory");
      else                           asm volatile("s_waitcnt vmcnt(2)" ::: "memory");
      __builtin_amdgcn_s_barrier();   // (4) one raw barrier per 2 K-steps
    }
  }

  // C/D layout (HW-verified, dtype-independent): col=lane&15, row=4*(lane>>4)+q
  float* pb = P + ((long)s * MN + tile_m * 64 + wid * 16) * 128;
#pragma unroll
  for (int c = 0; c < 8; ++c)
#pragma unroll
    for (int q = 0; q < 4; ++q)
      __builtin_nontemporal_store(acc[c][q] * sc,
                                  &pb[(g * 4 + q) * 128 + 16 * c + cl]);
}

// ---------------------------------------------------------------------------
// K3: LH = sum_s P[s] + b2 (tile in LDS); then
//     B2 = fp8frag(LH @ W4 * SB2);  R = LH @ res_w^T + res_b + b4
// ---------------------------------------------------------------------------
__global__ __launch_bounds__(256)
void k3_mid(const float* __restrict__ P, const float* __restrict__ b2,
            const float* __restrict__ W4, const float* __restrict__ res_w,
            const float* __restrict__ b4, const float* __restrict__ res_b,
            unsigned char* __restrict__ B2, float* __restrict__ Rr) {
  __shared__ __align__(16) float hs[64 * 128];
  const int t = threadIdx.x;
  const long rowbase = (long)blockIdx.x * 64;
  const long base = rowbase * 32;            // f32x4 units (128/4 per row)
  const f32x4* P0 = (const f32x4*)P + base;
  const f32x4* P1 = (const f32x4*)P + (long)MN * 32 + base;
  const f32x4* P2 = (const f32x4*)P + 2L * MN * 32 + base;
  const f32x4* P3 = (const f32x4*)P + 3L * MN * 32 + base;
  const f32x4* b2v = (const f32x4*)b2;
  f32x4* hl = (f32x4*)hs;
#pragma unroll
  for (int i = 0; i < 8; ++i) {
    int idx = t + 256 * i;
    f32x4 v = __builtin_nontemporal_load(P0 + idx);
    v += __builtin_nontemporal_load(P1 + idx);
    v += __builtin_nontemporal_load(P2 + idx);
    v += __builtin_nontemporal_load(P3 + idx);
    hl[idx] = v + b2v[idx & 31];
  }
  __syncthreads();
  const int r0 = (t >> 5) * 8;
  const int c0 = (t & 31) * 4;
  float acc2[8][4] = {};
  float accR[8][4] = {};
  for (int k = 0; k < 128; k += 4) {
    f32x4 w4v[4], rwv[4];
#pragma unroll
    for (int kk = 0; kk < 4; ++kk) w4v[kk] = *(const f32x4*)(W4 + (k + kk) * 128 + c0);
#pragma unroll
    for (int j = 0; j < 4; ++j) rwv[j] = *(const f32x4*)(res_w + (c0 + j) * 128 + k);
#pragma unroll
    for (int i = 0; i < 8; ++i) {
      f32x4 xv = *(const f32x4*)(hs + (r0 + i) * 128 + k);
#pragma unroll
      for (int kk = 0; kk < 4; ++kk)
#pragma unroll
        for (int j = 0; j < 4; ++j) {
          acc2[i][j] += xv[kk] * w4v[kk][j];
          accR[i][j] += xv[kk] * rwv[j][kk];
        }
    }
  }
  const long U = (rowbase + r0) >> 3;
  i32x4 wv0, wv1;
#pragma unroll
  for (int j = 0; j < 4; ++j) {
    int lo = __builtin_amdgcn_cvt_pk_fp8_f32(acc2[0][j] * SB2, acc2[1][j] * SB2, 0, false);
    lo     = __builtin_amdgcn_cvt_pk_fp8_f32(acc2[2][j] * SB2, acc2[3][j] * SB2, lo, true);
    int hi = __builtin_amdgcn_cvt_pk_fp8_f32(acc2[4][j] * SB2, acc2[5][j] * SB2, 0, false);
    hi     = __builtin_amdgcn_cvt_pk_fp8_f32(acc2[6][j] * SB2, acc2[7][j] * SB2, hi, true);
    if (j < 2) { wv0[2 * j] = lo; wv0[2 * j + 1] = hi; }
    else       { wv1[2 * (j - 2)] = lo; wv1[2 * (j - 2) + 1] = hi; }
  }
  *(i32x4*)(B2 + (U * 128 + c0) * 8)      = wv0;
  *(i32x4*)(B2 + (U * 128 + c0) * 8 + 16) = wv1;

  const f32x4 b4v = *(const f32x4*)(b4 + c0);
  const f32x4 rbv = *(const f32x4*)(res_b + c0);
#pragma unroll
  for (int i = 0; i < 8; ++i) {
    f32x4 rv;
#pragma unroll
    for (int j = 0; j < 4; ++j) rv[j] = accR[i][j];
    rv += b4v + rbv;
    *(f32x4*)(Rr + (rowbase + r0 + i) * 128 + c0) = rv;
  }
}

// ---------------------------------------------------------------------------
// K5: out = sum_s P[s] + R
// ---------------------------------------------------------------------------
__global__ __launch_bounds__(256)
void k5_out(const float* __restrict__ P, const float* __restrict__ Rr,
            float* __restrict__ out) {
  const long i = (long)blockIdx.x * 256 + threadIdx.x;   // f32x4 index
  const f32x4* P0 = (const f32x4*)P;
  const f32x4* P1 = P0 + (long)MN * 32;
  const f32x4* P2 = P0 + 2L * MN * 32;
  const f32x4* P3 = P0 + 3L * MN * 32;
  f32x4 v = __builtin_nontemporal_load(P0 + i);
  v += __builtin_nontemporal_load(P1 + i);
  v += __builtin_nontemporal_load(P2 + i);
  v += __builtin_nontemporal_load(P3 + i);
  v += *((const f32x4*)Rr + i);
  __builtin_nontemporal_store(v, (f32x4*)out + i);
}

extern "C" void kernel_launch(void* const* d_in, const int* in_sizes, int n_in,
                              void* d_out, int out_size, void* d_ws, size_t ws_size,
                              hipStream_t stream) {
  const float* x     = (const float*)d_in[0];
  const float* adj   = (const float*)d_in[1];
  const float* W2    = (const float*)d_in[2];
  const float* b2    = (const float*)d_in[3];
  const float* W4    = (const float*)d_in[4];
  const float* b4    = (const float*)d_in[5];
  const float* res_w = (const float*)d_in[6];
  const float* res_b = (const float*)d_in[7];
  float* out = (float*)d_out;

  char* ws = (char*)d_ws;
  unsigned char* B1 = (unsigned char*)ws;                  // 2 MB fp8-frag support1
  unsigned char* B2 = (unsigned char*)(ws + (4L << 20));   // 2 MB fp8-frag support2
  float* Rr = (float*)(ws + (8L << 20));                   // 8 MB residual + biases
  float* P  = (float*)(ws + (16L << 20));                  // 32 MB split-K partials
  unsigned char* A8 = (unsigned char*)(ws + (48L << 20));  // 256 MB fp8 adj

  const size_t need = (48L << 20) + (size_t)MN * MN;  // 318.8 MB
  const bool fp8_copy = ws_size >= need;

  k1_xw2<<<dim3(256), dim3(256), 0, stream>>>(x, W2, B1);
  if (fp8_copy) {
    big_mm<0><<<dim3(256 * SPLITS), dim3(256), 0, stream>>>(adj, nullptr, A8, B1, SC1, P);
    k3_mid<<<dim3(256), dim3(256), 0, stream>>>(P, b2, W4, res_w, b4, res_b, B2, Rr);
    big_mm<1><<<dim3(256 * SPLITS), dim3(256), 0, stream>>>(nullptr, A8, nullptr, B2, SC2, P);
  } else {
    big_mm<2><<<dim3(256 * SPLITS), dim3(256), 0, stream>>>(adj, nullptr, nullptr, B1, SC1, P);
    k3_mid<<<dim3(256), dim3(256), 0, stream>>>(P, b2, W4, res_w, b4, res_b, B2, Rr);
    big_mm<2><<<dim3(256 * SPLITS), dim3(256), 0, stream>>>(adj, nullptr, nullptr, B2, SC2, P);
  }
  k5_out<<<dim3(2048), dim3(256), 0, stream>>>(P, Rr, out);
}